// Round 16
// baseline (240.841 us; speedup 1.0000x reference)
//
#include <hip/hip_runtime.h>
#include <math.h>

#define NSIG   1023
#define BATCH  16
#define FT     1024          // F_BINS == T == 1024
#define KW     256           // truncated window taps, d in [-128, 127] (4 sigma)
#define RHALF  128
#define XPAD   1280          // 128 + 1023 + 127 (+2 pad)
#define HID    128

// ws layout (float offsets)
#define OFF_XCP  0u                       // 16*1280 = 20480
#define OFF_G    20480u                   // 256
#define OFF_HRAW 20736u                   // 2048  (fc1 accum, b-major: b*128+j)
#define OFF_TAB  22784u                   // bf16 hi/lo tables, 4 x 262144 u16
// u16 offsets within tab (f-major [f][256])
#define TAB_ECH  0u
#define TAB_ECL  262144u
#define TAB_ESH  524288u
#define TAB_ESL  786432u
#define OFF_PART 547072u                  // 512 x 2048 f32 fc1 partials (4 MB)
#define WS_NEED  6382592ull               // bytes needed for partials path

typedef int    i32x4  __attribute__((ext_vector_type(4)));
typedef float  f32x4  __attribute__((ext_vector_type(4)));
typedef __bf16 bf16x8 __attribute__((ext_vector_type(8)));
typedef unsigned short u16;

static __device__ __forceinline__ unsigned bfbits(float v) {
    unsigned u = __builtin_bit_cast(unsigned, v);
    return (u + 0x7fffu + ((u >> 16) & 1u)) >> 16;   // RNE round to bf16
}

// ---------------- K0: per-batch mean removal into zero-padded buffer ----------
__global__ void k_prep(const float* __restrict__ x, float* __restrict__ ws) {
    int b = blockIdx.x;
    __shared__ float red[256];
    float s = 0.f;
    for (int i = threadIdx.x; i < NSIG; i += 256) s += x[b * NSIG + i];
    red[threadIdx.x] = s;
    __syncthreads();
    for (int o = 128; o > 0; o >>= 1) {
        if (threadIdx.x < o) red[threadIdx.x] += red[threadIdx.x + o];
        __syncthreads();
    }
    float mean = red[0] * (1.0f / NSIG);
    float* xcp = ws + OFF_XCP + b * XPAD;
    for (int i = threadIdx.x; i < XPAD; i += 256) {
        int n = i - RHALF;
        xcp[i] = (n >= 0 && n < NSIG) ? (x[b * NSIG + n] - mean) : 0.f;
    }
}

// ---------------- K1: hi/lo bf16 sincos tables, f-major [f][256] --------------
__global__ void k_tables(const float* __restrict__ lambd, float* __restrict__ ws) {
    int bid = blockIdx.x;
    if (bid == 1024) {
        float sigma = fabsf(lambd[0]);
        float inv2s2 = 0.5f / (sigma * sigma);
        for (int i = threadIdx.x; i < KW; i += 256) {
            float d = (float)(i - RHALF);
            ws[OFF_G + i] = expf(-d * d * inv2s2);
        }
        for (int i = threadIdx.x; i < 2048; i += 256) ws[OFF_HRAW + i] = 0.f;
        return;
    }
    int idx = bid * 256 + threadIdx.x;       // 0 .. 262143 = f*256 + k
    int f = idx >> 8, k = idx & 255;
    int d = k - RHALF;
    int p = f * d;                           // |p| <= 130944, fits int
    int m = p % 2046; if (m < 0) m += 2046;  // exact phase mod 2pi
    double ang = (double)m * (6.283185307179586476925286766559 / 2046.0);
    double sv, cv;
    sincos(ang, &sv, &cv);
    float cf = (float)cv, sf = (float)sv;
    u16* tab = (u16*)(ws + OFF_TAB);
    unsigned chb = bfbits(cf);
    float chf = __builtin_bit_cast(float, chb << 16);
    unsigned clb = bfbits(cf - chf);
    unsigned shb = bfbits(sf);
    float shf = __builtin_bit_cast(float, shb << 16);
    unsigned slb = bfbits(sf - shf);
    tab[TAB_ECH + idx] = (u16)chb;
    tab[TAB_ECL + idx] = (u16)clb;
    tab[TAB_ESH + idx] = (u16)shb;
    tab[TAB_ESL + idx] = (u16)slb;
}

// ---------------- K2: spectrogram MFMA, full-y-in-LDS, barrier-free loop ------
// (unchanged from R13/R14/R15)
__global__ __launch_bounds__(512, 4) void k_spec(const float* __restrict__ ws,
                                                 float* __restrict__ out) {
    __shared__ u16 yH[64 * 256];   // 32 KB, swizzled [t][256]
    __shared__ u16 yL[64 * 256];   // 32 KB
    int t0 = blockIdx.x * 64, f0 = blockIdx.y * 128, b = blockIdx.z;
    int tid = threadIdx.x;
    int wave = tid >> 6, lane = tid & 63;
    int lo = lane & 15, hi4 = lane >> 4;
    const u16* tab = (const u16*)(ws + OFF_TAB);
    const float* xcp = ws + OFF_XCP + b * XPAD;
    const float* gw  = ws + OFF_G;

    #pragma unroll
    for (int i = 0; i < 4; i++) {
        int idx = tid + i * 512;             // 0..2047
        int t = idx >> 5, kg = idx & 31;
        int k = kg * 8;
        const float* xp = xcp + t0 + t + k;
        float4 g0 = *(const float4*)&gw[k];
        float4 g1 = *(const float4*)&gw[k + 4];
        float yv[8];
        yv[0] = xp[0] * g0.x; yv[1] = xp[1] * g0.y;
        yv[2] = xp[2] * g0.z; yv[3] = xp[3] * g0.w;
        yv[4] = xp[4] * g1.x; yv[5] = xp[5] * g1.y;
        yv[6] = xp[6] * g1.z; yv[7] = xp[7] * g1.w;
        unsigned hb[8], lb[8];
        #pragma unroll
        for (int j = 0; j < 8; j++) {
            unsigned u = __builtin_bit_cast(unsigned, yv[j]);
            unsigned h = (u + 0x7fffu + ((u >> 16) & 1u)) & 0xffff0000u;
            float hf = __builtin_bit_cast(float, h);
            hb[j] = h >> 16;
            lb[j] = bfbits(yv[j] - hf);
        }
        i32x4 ph, pl;
        ph.x = (int)(hb[0] | (hb[1] << 16)); ph.y = (int)(hb[2] | (hb[3] << 16));
        ph.z = (int)(hb[4] | (hb[5] << 16)); ph.w = (int)(hb[6] | (hb[7] << 16));
        pl.x = (int)(lb[0] | (lb[1] << 16)); pl.y = (int)(lb[2] | (lb[3] << 16));
        pl.z = (int)(lb[4] | (lb[5] << 16)); pl.w = (int)(lb[6] | (lb[7] << 16));
        int wb = ((t * 512 + kg * 16) ^ ((t & 7) << 4));
        *(i32x4*)((char*)yH + wb) = ph;
        *(i32x4*)((char*)yL + wb) = pl;
    }
    __syncthreads();

    size_t arow = (size_t)(f0 + wave * 16 + lo) * 256 + hi4 * 8;
    const u16* pech = tab + TAB_ECH + arow;
    const u16* pecl = tab + TAB_ECL + arow;
    const u16* pesh = tab + TAB_ESH + arow;
    const u16* pesl = tab + TAB_ESL + arow;

    f32x4 reA[4], imA[4];
    #pragma unroll
    for (int i = 0; i < 4; i++) {
        reA[i] = (f32x4){0.f, 0.f, 0.f, 0.f};
        imA[i] = (f32x4){0.f, 0.f, 0.f, 0.f};
    }

    #pragma unroll 2
    for (int c = 0; c < 8; c++) {
        i32x4 ech = *(const i32x4*)(pech + c * 32);
        i32x4 ecl = *(const i32x4*)(pecl + c * 32);
        i32x4 esh = *(const i32x4*)(pesh + c * 32);
        i32x4 esl = *(const i32x4*)(pesl + c * 32);
        #pragma unroll
        for (int tt = 0; tt < 4; tt++) {
            int tr = tt * 16 + lo;
            int rb = ((tr * 512 + c * 64 + hi4 * 16) ^ ((tr & 7) << 4));
            i32x4 yh = *(const i32x4*)((const char*)yH + rb);
            i32x4 yl = *(const i32x4*)((const char*)yL + rb);
            asm("v_mfma_f32_16x16x32_bf16 %0, %1, %2, %0" : "+v"(reA[tt]) : "v"(ech), "v"(yh));
            asm("v_mfma_f32_16x16x32_bf16 %0, %1, %2, %0" : "+v"(imA[tt]) : "v"(esh), "v"(yh));
            asm("v_mfma_f32_16x16x32_bf16 %0, %1, %2, %0" : "+v"(reA[tt]) : "v"(ech), "v"(yl));
            asm("v_mfma_f32_16x16x32_bf16 %0, %1, %2, %0" : "+v"(imA[tt]) : "v"(esh), "v"(yl));
            asm("v_mfma_f32_16x16x32_bf16 %0, %1, %2, %0" : "+v"(reA[tt]) : "v"(ecl), "v"(yh));
            asm("v_mfma_f32_16x16x32_bf16 %0, %1, %2, %0" : "+v"(imA[tt]) : "v"(esl), "v"(yh));
        }
    }
    asm volatile("s_nop 7\n\ts_nop 7");   // MFMA->VALU read hazard guard

    float* dS = out + 160;
    #pragma unroll
    for (int tt = 0; tt < 4; tt++) {
        #pragma unroll
        for (int r = 0; r < 4; r++) {
            int f = f0 + wave * 16 + hi4 * 4 + r;
            float re = reA[tt][r], im = imA[tt][r];
            dS[((size_t)b << 20) + (size_t)f * 1024 + t0 + tt * 16 + lo] = re * re + im * im;
        }
    }
}

// ---------------- K3: fc1 — R15 staging + contention-free epilogue ------------
// Loop identical to R15 (whole-row 1 KB staging, private dbuf, vmcnt(16)).
// Epilogue: per-block partials to a private 4 MB slab (plain coalesced stores)
// instead of 1M device-scope atomics onto one 8 KB array; k_red reduces.
// Fallback (part==nullptr): R15's atomic path.
static __device__ __forceinline__ bf16x8 packc4(float4 a, float4 b) {
    bf16x8 r;
    r[0] = (__bf16)a.x; r[1] = (__bf16)a.y; r[2] = (__bf16)a.z; r[3] = (__bf16)a.w;
    r[4] = (__bf16)b.x; r[5] = (__bf16)b.y; r[6] = (__bf16)b.z; r[7] = (__bf16)b.w;
    return r;
}
static __device__ __forceinline__ bf16x8 packcv(f32x4 a, f32x4 b) {
    bf16x8 r;
    r[0] = (__bf16)a.x; r[1] = (__bf16)a.y; r[2] = (__bf16)a.z; r[3] = (__bf16)a.w;
    r[4] = (__bf16)b.x; r[5] = (__bf16)b.y; r[6] = (__bf16)b.z; r[7] = (__bf16)b.w;
    return r;
}

// stage [16 rows][256 floats]: instr i reads row i's 1 KB contiguous run.
static __device__ __forceinline__ void stageC(const float* base, float* dst, int laneByte) {
    #pragma unroll
    for (int i = 0; i < 16; i++) {
        const float* src = base + ((size_t)i << 20)
                         + ((laneByte ^ ((i & 7) << 4)) >> 2);
        __builtin_amdgcn_global_load_lds(
            (const __attribute__((address_space(1))) void*)src,
            (__attribute__((address_space(3))) void*)((char*)dst + i * 1024),
            16, 0, 0);
    }
}

__global__ __launch_bounds__(256, 1) void k_fc1(const float* __restrict__ S,
                                                const float* __restrict__ W1,
                                                float* __restrict__ hraw,
                                                float* __restrict__ part) {
    __shared__ float Wl[4][2][4096];   // [wave][buf][16 KB] = 128 KB
    int tid = threadIdx.x;
    int wave = tid >> 6, lane = tid & 63;
    int bq = lane >> 4, lo = lane & 15;
    int ks = (blockIdx.x << 2) | wave;           // 0..2047 k-stripe
    size_t kb = (size_t)ks * 512;

    int laneByte = lane << 4;                    // 16 B per lane within 1 KB row
    int sw = (lo & 7) << 4;

    const float* Sp = S + ((size_t)lo << 20) + kb + bq * 8;
    float* buf0 = &Wl[wave][0][0];
    float* buf1 = &Wl[wave][1][0];

    // prologue: stage chunk 0 (jt=0, s=0) first so S waits don't stall it
    stageC(W1 + kb, buf0, laneByte);

    // ---- preload + pack ALL S for this stripe (read once grid-wide) ----
    bf16x8 af[4][4];
    #pragma unroll
    for (int s = 0; s < 4; s++) {
        #pragma unroll
        for (int q = 0; q < 4; q++) {
            float4 a0 = *(const float4*)(Sp + s * 128 + q * 32);
            float4 a1 = *(const float4*)(Sp + s * 128 + q * 32 + 4);
            af[s][q] = packc4(a0, a1);
        }
    }

    f32x4 acc[8];
    #pragma unroll
    for (int j = 0; j < 8; j++) acc[j] = (f32x4){0.f, 0.f, 0.f, 0.f};

    #pragma unroll
    for (int c = 0; c < 16; c++) {
        const int jt = c >> 1, sh = c & 1;
        if (c < 15) {
            const int cn = c + 1, jn = cn >> 1, sn = cn & 1;
            stageC(W1 + ((size_t)(jn * 16) << 20) + kb + sn * 256,
                   (c & 1) ? buf0 : buf1, laneByte);
            asm volatile("s_waitcnt vmcnt(16)" ::: "memory");
        } else {
            asm volatile("s_waitcnt vmcnt(0)" ::: "memory");
        }
        const char* wb = (const char*)((c & 1) ? buf1 : buf0);
        #pragma unroll
        for (int q = 0; q < 8; q++) {
            const int ki = sh * 8 + q;           // 32-k step within stripe
            int cb = q * 128 + bq * 32;
            f32x4 w0 = *(const f32x4*)(wb + lo * 1024 + (cb ^ sw));
            f32x4 w1 = *(const f32x4*)(wb + lo * 1024 + ((cb + 16) ^ sw));
            acc[jt] = __builtin_amdgcn_mfma_f32_16x16x32_bf16(af[ki >> 2][ki & 3],
                                                              packcv(w0, w1),
                                                              acc[jt], 0, 0, 0);
        }
    }

    // epilogue: per-wave partials -> LDS, cross-wave reduce, then either
    // contention-free partials store (part path) or atomics (fallback).
    float* red = &Wl[wave][0][0];
    #pragma unroll
    for (int jt = 0; jt < 8; jt++) {
        #pragma unroll
        for (int r = 0; r < 4; r++) {
            red[(bq * 4 + r) * 128 + jt * 16 + lo] = acc[jt][r];
        }
    }
    __syncthreads();
    if (part != nullptr) {
        float* dst = part + (size_t)blockIdx.x * 2048;
        for (int p = tid; p < 2048; p += 256) {
            dst[p] = Wl[0][0][p] + Wl[1][0][p] + Wl[2][0][p] + Wl[3][0][p];
        }
    } else {
        for (int p = tid; p < 2048; p += 256) {
            float v = Wl[0][0][p] + Wl[1][0][p] + Wl[2][0][p] + Wl[3][0][p];
            atomicAdd(&hraw[p], v);
        }
    }
}

// ---------------- K3b: reduce 512 x 2048 partials -> hraw ---------------------
__global__ void k_red(const float* __restrict__ part, float* __restrict__ hraw) {
    int p = blockIdx.x * 256 + threadIdx.x;   // 0..2047
    float s0 = 0.f, s1 = 0.f, s2 = 0.f, s3 = 0.f;
    float s4 = 0.f, s5 = 0.f, s6 = 0.f, s7 = 0.f;
    #pragma unroll 4
    for (int i = 0; i < 512; i += 8) {
        s0 += part[(size_t)(i    ) * 2048 + p];
        s1 += part[(size_t)(i + 1) * 2048 + p];
        s2 += part[(size_t)(i + 2) * 2048 + p];
        s3 += part[(size_t)(i + 3) * 2048 + p];
        s4 += part[(size_t)(i + 4) * 2048 + p];
        s5 += part[(size_t)(i + 5) * 2048 + p];
        s6 += part[(size_t)(i + 6) * 2048 + p];
        s7 += part[(size_t)(i + 7) * 2048 + p];
    }
    hraw[p] = ((s0 + s1) + (s2 + s3)) + ((s4 + s5) + (s6 + s7));
}

// ---------------- K4: bias+relu+fc2 head --------------------------------------
__global__ void k_head(const float* __restrict__ hraw, const float* __restrict__ b1,
                       const float* __restrict__ W2, const float* __restrict__ b2,
                       float* __restrict__ out) {
    __shared__ float hl[2048];
    int tid = threadIdx.x;
    for (int p = tid; p < 2048; p += 256) {
        float hv = hraw[p] + b1[p & 127];
        hl[p] = hv > 0.f ? hv : 0.f;
    }
    __syncthreads();
    if (tid < 160) {
        int b = tid / 10, c = tid - b * 10;
        float s = b2[c];
        for (int j = 0; j < 128; j++) s += hl[b * 128 + j] * W2[c * 128 + j];
        out[b * 10 + c] = s;
    }
}

extern "C" void kernel_launch(void* const* d_in, const int* in_sizes, int n_in,
                              void* d_out, int out_size, void* d_ws, size_t ws_size,
                              hipStream_t stream) {
    const float* x     = (const float*)d_in[0];
    const float* lambd = (const float*)d_in[1];
    const float* W1    = (const float*)d_in[2];
    const float* b1    = (const float*)d_in[3];
    const float* W2    = (const float*)d_in[4];
    const float* b2    = (const float*)d_in[5];
    float* out = (float*)d_out;
    float* ws  = (float*)d_ws;
    bool big = (ws_size >= WS_NEED);
    float* part = big ? (ws + OFF_PART) : nullptr;

    hipLaunchKernelGGL(k_prep,   dim3(16),         dim3(256), 0, stream, x, ws);
    hipLaunchKernelGGL(k_tables, dim3(1025),       dim3(256), 0, stream, lambd, ws);
    hipLaunchKernelGGL(k_spec,   dim3(16, 8, 16),  dim3(512), 0, stream, ws, out);
    hipLaunchKernelGGL(k_fc1,    dim3(512),        dim3(256), 0, stream,
                       out + 160, W1, ws + OFF_HRAW, part);
    if (big) {
        hipLaunchKernelGGL(k_red, dim3(8),         dim3(256), 0, stream,
                           part, ws + OFF_HRAW);
    }
    hipLaunchKernelGGL(k_head,   dim3(1),          dim3(256), 0, stream,
                       ws + OFF_HRAW, b1, W2, b2, out);
}

// Round 17
// 201.748 us; speedup vs baseline: 1.1938x; 1.1938x over previous
//
#include <hip/hip_runtime.h>
#include <math.h>

#define NSIG   1023
#define BATCH  16
#define FT     1024          // F_BINS == T == 1024
#define KW     256           // truncated window taps, d in [-128, 127] (4 sigma)
#define RHALF  128
#define XPAD   1280          // 128 + 1023 + 127 (+2 pad)
#define HID    128

// ws layout (float offsets)
#define OFF_XCP  0u                       // 16*1280 = 20480
#define OFF_G    20480u                   // 256
#define OFF_HRAW 20736u                   // 2048  (fc1 accum, b-major: b*128+j)
#define OFF_TAB  22784u                   // bf16 hi/lo tables, 4 x 262144 u16
// u16 offsets within tab (f-major [f][256])
#define TAB_ECH  0u
#define TAB_ECL  262144u
#define TAB_ESH  524288u
#define TAB_ESL  786432u

typedef int    i32x4  __attribute__((ext_vector_type(4)));
typedef float  f32x4  __attribute__((ext_vector_type(4)));
typedef __bf16 bf16x8 __attribute__((ext_vector_type(8)));
typedef unsigned short u16;

static __device__ __forceinline__ unsigned bfbits(float v) {
    unsigned u = __builtin_bit_cast(unsigned, v);
    return (u + 0x7fffu + ((u >> 16) & 1u)) >> 16;   // RNE round to bf16
}

// ---------------- K0: per-batch mean removal into zero-padded buffer ----------
__global__ void k_prep(const float* __restrict__ x, float* __restrict__ ws) {
    int b = blockIdx.x;
    __shared__ float red[256];
    float s = 0.f;
    for (int i = threadIdx.x; i < NSIG; i += 256) s += x[b * NSIG + i];
    red[threadIdx.x] = s;
    __syncthreads();
    for (int o = 128; o > 0; o >>= 1) {
        if (threadIdx.x < o) red[threadIdx.x] += red[threadIdx.x + o];
        __syncthreads();
    }
    float mean = red[0] * (1.0f / NSIG);
    float* xcp = ws + OFF_XCP + b * XPAD;
    for (int i = threadIdx.x; i < XPAD; i += 256) {
        int n = i - RHALF;
        xcp[i] = (n >= 0 && n < NSIG) ? (x[b * NSIG + n] - mean) : 0.f;
    }
}

// ---------------- K1: hi/lo bf16 sincos tables, f-major [f][256] --------------
__global__ void k_tables(const float* __restrict__ lambd, float* __restrict__ ws) {
    int bid = blockIdx.x;
    if (bid == 1024) {
        float sigma = fabsf(lambd[0]);
        float inv2s2 = 0.5f / (sigma * sigma);
        for (int i = threadIdx.x; i < KW; i += 256) {
            float d = (float)(i - RHALF);
            ws[OFF_G + i] = expf(-d * d * inv2s2);
        }
        for (int i = threadIdx.x; i < 2048; i += 256) ws[OFF_HRAW + i] = 0.f;
        return;
    }
    int idx = bid * 256 + threadIdx.x;       // 0 .. 262143 = f*256 + k
    int f = idx >> 8, k = idx & 255;
    int d = k - RHALF;
    int p = f * d;                           // |p| <= 130944, fits int
    int m = p % 2046; if (m < 0) m += 2046;  // exact phase mod 2pi
    double ang = (double)m * (6.283185307179586476925286766559 / 2046.0);
    double sv, cv;
    sincos(ang, &sv, &cv);
    float cf = (float)cv, sf = (float)sv;
    u16* tab = (u16*)(ws + OFF_TAB);
    unsigned chb = bfbits(cf);
    float chf = __builtin_bit_cast(float, chb << 16);
    unsigned clb = bfbits(cf - chf);
    unsigned shb = bfbits(sf);
    float shf = __builtin_bit_cast(float, shb << 16);
    unsigned slb = bfbits(sf - shf);
    tab[TAB_ECH + idx] = (u16)chb;
    tab[TAB_ECL + idx] = (u16)clb;
    tab[TAB_ESH + idx] = (u16)shb;
    tab[TAB_ESL + idx] = (u16)slb;
}

// ---------------- K2: spectrogram MFMA, full-y-in-LDS, barrier-free loop ------
// (unchanged from R13/R14/R15)
__global__ __launch_bounds__(512, 4) void k_spec(const float* __restrict__ ws,
                                                 float* __restrict__ out) {
    __shared__ u16 yH[64 * 256];   // 32 KB, swizzled [t][256]
    __shared__ u16 yL[64 * 256];   // 32 KB
    int t0 = blockIdx.x * 64, f0 = blockIdx.y * 128, b = blockIdx.z;
    int tid = threadIdx.x;
    int wave = tid >> 6, lane = tid & 63;
    int lo = lane & 15, hi4 = lane >> 4;
    const u16* tab = (const u16*)(ws + OFF_TAB);
    const float* xcp = ws + OFF_XCP + b * XPAD;
    const float* gw  = ws + OFF_G;

    #pragma unroll
    for (int i = 0; i < 4; i++) {
        int idx = tid + i * 512;             // 0..2047
        int t = idx >> 5, kg = idx & 31;
        int k = kg * 8;
        const float* xp = xcp + t0 + t + k;
        float4 g0 = *(const float4*)&gw[k];
        float4 g1 = *(const float4*)&gw[k + 4];
        float yv[8];
        yv[0] = xp[0] * g0.x; yv[1] = xp[1] * g0.y;
        yv[2] = xp[2] * g0.z; yv[3] = xp[3] * g0.w;
        yv[4] = xp[4] * g1.x; yv[5] = xp[5] * g1.y;
        yv[6] = xp[6] * g1.z; yv[7] = xp[7] * g1.w;
        unsigned hb[8], lb[8];
        #pragma unroll
        for (int j = 0; j < 8; j++) {
            unsigned u = __builtin_bit_cast(unsigned, yv[j]);
            unsigned h = (u + 0x7fffu + ((u >> 16) & 1u)) & 0xffff0000u;
            float hf = __builtin_bit_cast(float, h);
            hb[j] = h >> 16;
            lb[j] = bfbits(yv[j] - hf);
        }
        i32x4 ph, pl;
        ph.x = (int)(hb[0] | (hb[1] << 16)); ph.y = (int)(hb[2] | (hb[3] << 16));
        ph.z = (int)(hb[4] | (hb[5] << 16)); ph.w = (int)(hb[6] | (hb[7] << 16));
        pl.x = (int)(lb[0] | (lb[1] << 16)); pl.y = (int)(lb[2] | (lb[3] << 16));
        pl.z = (int)(lb[4] | (lb[5] << 16)); pl.w = (int)(lb[6] | (lb[7] << 16));
        int wb = ((t * 512 + kg * 16) ^ ((t & 7) << 4));
        *(i32x4*)((char*)yH + wb) = ph;
        *(i32x4*)((char*)yL + wb) = pl;
    }
    __syncthreads();

    size_t arow = (size_t)(f0 + wave * 16 + lo) * 256 + hi4 * 8;
    const u16* pech = tab + TAB_ECH + arow;
    const u16* pecl = tab + TAB_ECL + arow;
    const u16* pesh = tab + TAB_ESH + arow;
    const u16* pesl = tab + TAB_ESL + arow;

    f32x4 reA[4], imA[4];
    #pragma unroll
    for (int i = 0; i < 4; i++) {
        reA[i] = (f32x4){0.f, 0.f, 0.f, 0.f};
        imA[i] = (f32x4){0.f, 0.f, 0.f, 0.f};
    }

    #pragma unroll 2
    for (int c = 0; c < 8; c++) {
        i32x4 ech = *(const i32x4*)(pech + c * 32);
        i32x4 ecl = *(const i32x4*)(pecl + c * 32);
        i32x4 esh = *(const i32x4*)(pesh + c * 32);
        i32x4 esl = *(const i32x4*)(pesl + c * 32);
        #pragma unroll
        for (int tt = 0; tt < 4; tt++) {
            int tr = tt * 16 + lo;
            int rb = ((tr * 512 + c * 64 + hi4 * 16) ^ ((tr & 7) << 4));
            i32x4 yh = *(const i32x4*)((const char*)yH + rb);
            i32x4 yl = *(const i32x4*)((const char*)yL + rb);
            asm("v_mfma_f32_16x16x32_bf16 %0, %1, %2, %0" : "+v"(reA[tt]) : "v"(ech), "v"(yh));
            asm("v_mfma_f32_16x16x32_bf16 %0, %1, %2, %0" : "+v"(imA[tt]) : "v"(esh), "v"(yh));
            asm("v_mfma_f32_16x16x32_bf16 %0, %1, %2, %0" : "+v"(reA[tt]) : "v"(ech), "v"(yl));
            asm("v_mfma_f32_16x16x32_bf16 %0, %1, %2, %0" : "+v"(imA[tt]) : "v"(esh), "v"(yl));
            asm("v_mfma_f32_16x16x32_bf16 %0, %1, %2, %0" : "+v"(reA[tt]) : "v"(ecl), "v"(yh));
            asm("v_mfma_f32_16x16x32_bf16 %0, %1, %2, %0" : "+v"(imA[tt]) : "v"(esl), "v"(yh));
        }
    }
    asm volatile("s_nop 7\n\ts_nop 7");   // MFMA->VALU read hazard guard

    float* dS = out + 160;
    #pragma unroll
    for (int tt = 0; tt < 4; tt++) {
        #pragma unroll
        for (int r = 0; r < 4; r++) {
            int f = f0 + wave * 16 + hi4 * 4 + r;
            float re = reA[tt][r], im = imA[tt][r];
            dS[((size_t)b << 20) + (size_t)f * 1024 + t0 + tt * 16 + lo] = re * re + im * im;
        }
    }
}

// ---------------- K3: fc1 — reg-staged W1 (coalesced float4 loads + ds_write) -
// h[b,j] = sum_i S[b,i]*W1[j,i]. 512 blocks x 4 waves; wave owns k-stripe
// ks = blockIdx*4+wave (512 k), all 128 j. Staging path switched from
// global_load_lds (ceiling ~4.3 TB/s across 6 variants) to PLAIN float4
// register loads (m13-proven 6.3 TB/s path) + ds_write_b128 into a per-wave
// private single 8 KB LDS buffer (DS pipe is per-wave in-order -> read-before-
// overwrite safe, no barriers). Chunk = [16 rows][128 k] = 8 KB; double-buffer
// lives in registers st[8]; loads for c+1 issue before consuming c, one
// vmcnt(0)+compiler-barrier before the writes. s-outer/jt-inner keeps only
// af[4] live (~110 VGPR). 12 waves/CU.
static __device__ __forceinline__ bf16x8 packc4(float4 a, float4 b) {
    bf16x8 r;
    r[0] = (__bf16)a.x; r[1] = (__bf16)a.y; r[2] = (__bf16)a.z; r[3] = (__bf16)a.w;
    r[4] = (__bf16)b.x; r[5] = (__bf16)b.y; r[6] = (__bf16)b.z; r[7] = (__bf16)b.w;
    return r;
}
static __device__ __forceinline__ bf16x8 packcv(f32x4 a, f32x4 b) {
    bf16x8 r;
    r[0] = (__bf16)a.x; r[1] = (__bf16)a.y; r[2] = (__bf16)a.z; r[3] = (__bf16)a.w;
    r[4] = (__bf16)b.x; r[5] = (__bf16)b.y; r[6] = (__bf16)b.z; r[7] = (__bf16)b.w;
    return r;
}

__global__ __launch_bounds__(256, 3) void k_fc1(const float* __restrict__ S,
                                                const float* __restrict__ W1,
                                                float* __restrict__ hraw) {
    __shared__ float Wl[4][2048];   // [wave][8 KB] = 32 KB
    int tid = threadIdx.x;
    int wave = tid >> 6, lane = tid & 63;
    int bq = lane >> 4, lo = lane & 15;
    int ks = (blockIdx.x << 2) | wave;           // 0..2047 k-stripe
    size_t kb = (size_t)ks * 512;

    // staging geometry: instr i covers local rows {2i, 2i+1(lane>>5)}, 16 B/lane
    int lr0 = lane >> 5;                         // 0..1 row-within-pair
    int c16 = lane & 31;                         // 16 B column index (0..31)
    int sw = (lo & 7) << 4;

    const float* Sp = S + ((size_t)lo << 20) + kb + bq * 8;
    float* buf = &Wl[wave][0];

    // per-lane LDS write addresses for the 8 staging stores (static per i)
    // row = 2i + lr0; addr = row*512 + ((c16*16) ^ ((row&7)<<4))
    f32x4 st0, st1, st2, st3, st4, st5, st6, st7;
    #define LD_CHUNK(JT, SS)                                                     \
        {                                                                        \
            const float* _b = W1 + ((size_t)((JT) * 16) << 20) + kb + (SS) * 128;\
            st0 = *(const f32x4*)(_b + ((size_t)(0  + lr0) << 20) + c16 * 4);    \
            st1 = *(const f32x4*)(_b + ((size_t)(2  + lr0) << 20) + c16 * 4);    \
            st2 = *(const f32x4*)(_b + ((size_t)(4  + lr0) << 20) + c16 * 4);    \
            st3 = *(const f32x4*)(_b + ((size_t)(6  + lr0) << 20) + c16 * 4);    \
            st4 = *(const f32x4*)(_b + ((size_t)(8  + lr0) << 20) + c16 * 4);    \
            st5 = *(const f32x4*)(_b + ((size_t)(10 + lr0) << 20) + c16 * 4);    \
            st6 = *(const f32x4*)(_b + ((size_t)(12 + lr0) << 20) + c16 * 4);    \
            st7 = *(const f32x4*)(_b + ((size_t)(14 + lr0) << 20) + c16 * 4);    \
        }
    #define ST_CHUNK()                                                           \
        {                                                                        \
            *(f32x4*)((char*)buf + ((0  + lr0) * 512 + ((c16 * 16) ^ (((0  + lr0) & 7) << 4)))) = st0; \
            *(f32x4*)((char*)buf + ((2  + lr0) * 512 + ((c16 * 16) ^ (((2  + lr0) & 7) << 4)))) = st1; \
            *(f32x4*)((char*)buf + ((4  + lr0) * 512 + ((c16 * 16) ^ (((4  + lr0) & 7) << 4)))) = st2; \
            *(f32x4*)((char*)buf + ((6  + lr0) * 512 + ((c16 * 16) ^ (((6  + lr0) & 7) << 4)))) = st3; \
            *(f32x4*)((char*)buf + ((8  + lr0) * 512 + ((c16 * 16) ^ (((8  + lr0) & 7) << 4)))) = st4; \
            *(f32x4*)((char*)buf + ((10 + lr0) * 512 + ((c16 * 16) ^ (((10 + lr0) & 7) << 4)))) = st5; \
            *(f32x4*)((char*)buf + ((12 + lr0) * 512 + ((c16 * 16) ^ (((12 + lr0) & 7) << 4)))) = st6; \
            *(f32x4*)((char*)buf + ((14 + lr0) * 512 + ((c16 * 16) ^ (((14 + lr0) & 7) << 4)))) = st7; \
        }

    f32x4 acc[8];
    #pragma unroll
    for (int j = 0; j < 8; j++) acc[j] = (f32x4){0.f, 0.f, 0.f, 0.f};

    // prologue: chunk 0 (s=0, jt=0) regs -> LDS
    LD_CHUNK(0, 0);
    asm volatile("s_waitcnt vmcnt(0)" ::: "memory");
    ST_CHUNK();

    bf16x8 af0, af1, af2, af3;

    #pragma unroll
    for (int c = 0; c < 32; c++) {
        const int s = c >> 3, jt = c & 7;
        if (jt == 0) {   // load this s-phase's S fragments (L3-resident)
            const float* sp = Sp + s * 128;
            float4 a0 = *(const float4*)(sp);
            float4 a1 = *(const float4*)(sp + 4);
            float4 a2 = *(const float4*)(sp + 32);
            float4 a3 = *(const float4*)(sp + 36);
            float4 a4 = *(const float4*)(sp + 64);
            float4 a5 = *(const float4*)(sp + 68);
            float4 a6 = *(const float4*)(sp + 96);
            float4 a7 = *(const float4*)(sp + 100);
            af0 = packc4(a0, a1); af1 = packc4(a2, a3);
            af2 = packc4(a4, a5); af3 = packc4(a6, a7);
        }
        if (c < 31) {    // issue next chunk's global loads (in flight during consume)
            const int cn = c + 1, sn = cn >> 3, jn = cn & 7;
            LD_CHUNK(jn, sn);
        }
        // consume chunk c from LDS
        {
            int cb0 = bq * 32;
            f32x4 w0 = *(const f32x4*)((char*)buf + lo * 512 + ((cb0      ) ^ sw));
            f32x4 w1 = *(const f32x4*)((char*)buf + lo * 512 + ((cb0 +  16) ^ sw));
            acc[jt] = __builtin_amdgcn_mfma_f32_16x16x32_bf16(af0, packcv(w0, w1), acc[jt], 0, 0, 0);
            f32x4 w2 = *(const f32x4*)((char*)buf + lo * 512 + ((cb0 + 128) ^ sw));
            f32x4 w3 = *(const f32x4*)((char*)buf + lo * 512 + ((cb0 + 144) ^ sw));
            acc[jt] = __builtin_amdgcn_mfma_f32_16x16x32_bf16(af1, packcv(w2, w3), acc[jt], 0, 0, 0);
            f32x4 w4 = *(const f32x4*)((char*)buf + lo * 512 + ((cb0 + 256) ^ sw));
            f32x4 w5 = *(const f32x4*)((char*)buf + lo * 512 + ((cb0 + 272) ^ sw));
            acc[jt] = __builtin_amdgcn_mfma_f32_16x16x32_bf16(af2, packcv(w4, w5), acc[jt], 0, 0, 0);
            f32x4 w6 = *(const f32x4*)((char*)buf + lo * 512 + ((cb0 + 384) ^ sw));
            f32x4 w7 = *(const f32x4*)((char*)buf + lo * 512 + ((cb0 + 400) ^ sw));
            acc[jt] = __builtin_amdgcn_mfma_f32_16x16x32_bf16(af3, packcv(w6, w7), acc[jt], 0, 0, 0);
        }
        if (c < 31) {    // wait for regs, then overwrite the private buffer
            asm volatile("s_waitcnt vmcnt(0)" ::: "memory");
            ST_CHUNK();
        }
    }
    #undef LD_CHUNK
    #undef ST_CHUNK
    asm volatile("s_nop 7\n\ts_nop 7");   // MFMA->VALU read hazard guard

    // epilogue: per-wave partials -> LDS, cross-wave reduce, 2048 atomics/block
    float* red = &Wl[wave][0];
    #pragma unroll
    for (int jt = 0; jt < 8; jt++) {
        #pragma unroll
        for (int r = 0; r < 4; r++) {
            red[(bq * 4 + r) * 128 + jt * 16 + lo] = acc[jt][r];
        }
    }
    __syncthreads();
    for (int p = tid; p < 2048; p += 256) {
        float v = Wl[0][p] + Wl[1][p] + Wl[2][p] + Wl[3][p];
        atomicAdd(&hraw[p], v);
    }
}

// ---------------- K4: bias+relu+fc2 head --------------------------------------
__global__ void k_head(const float* __restrict__ hraw, const float* __restrict__ b1,
                       const float* __restrict__ W2, const float* __restrict__ b2,
                       float* __restrict__ out) {
    __shared__ float hl[2048];
    int tid = threadIdx.x;
    for (int p = tid; p < 2048; p += 256) {
        float hv = hraw[p] + b1[p & 127];
        hl[p] = hv > 0.f ? hv : 0.f;
    }
    __syncthreads();
    if (tid < 160) {
        int b = tid / 10, c = tid - b * 10;
        float s = b2[c];
        for (int j = 0; j < 128; j++) s += hl[b * 128 + j] * W2[c * 128 + j];
        out[b * 10 + c] = s;
    }
}

extern "C" void kernel_launch(void* const* d_in, const int* in_sizes, int n_in,
                              void* d_out, int out_size, void* d_ws, size_t ws_size,
                              hipStream_t stream) {
    const float* x     = (const float*)d_in[0];
    const float* lambd = (const float*)d_in[1];
    const float* W1    = (const float*)d_in[2];
    const float* b1    = (const float*)d_in[3];
    const float* W2    = (const float*)d_in[4];
    const float* b2    = (const float*)d_in[5];
    float* out = (float*)d_out;
    float* ws  = (float*)d_ws;

    hipLaunchKernelGGL(k_prep,   dim3(16),         dim3(256), 0, stream, x, ws);
    hipLaunchKernelGGL(k_tables, dim3(1025),       dim3(256), 0, stream, lambd, ws);
    hipLaunchKernelGGL(k_spec,   dim3(16, 8, 16),  dim3(512), 0, stream, ws, out);
    hipLaunchKernelGGL(k_fc1,    dim3(512),        dim3(256), 0, stream,
                       out + 160, W1, ws + OFF_HRAW);
    hipLaunchKernelGGL(k_head,   dim3(1),          dim3(256), 0, stream,
                       ws + OFF_HRAW, b1, W2, b2, out);
}